// Round 2
// baseline (776.144 us; speedup 1.0000x reference)
//
#include <hip/hip_runtime.h>
#include <hip/hip_bf16.h>

typedef _Float16 f16;
typedef f16 f16x4 __attribute__((ext_vector_type(4)));
typedef f16 f16x8 __attribute__((ext_vector_type(8)));
typedef float f32x4 __attribute__((ext_vector_type(4)));
typedef float f32x16 __attribute__((ext_vector_type(16)));

#define MT 256          // points per block
#define LDST 260        // f16 LDS row stride: 520 B -> 2-way (free) bank pattern, 8B aligned
#define INV2PI 0.15915494309189535f

// ---------------- prep: Wt[layer][c][k] = (f16) wh[layer][k][c] ----------------
__global__ __launch_bounds__(256)
void prep_wt(const float* __restrict__ wh, f16* __restrict__ wt) {
    __shared__ float tile[32][33];
    const int b = blockIdx.x;              // 256 blocks: layer(2b) | kt(3b) | ct(3b)
    const int layer = b >> 6, kt = (b >> 3) & 7, ct = b & 7;
    const int tx = threadIdx.x & 31, ty = threadIdx.x >> 5;   // 32 x 8
    const float* src = wh + layer * 65536;
    f16* dst = wt + layer * 65536;
#pragma unroll
    for (int r = 0; r < 4; r++) {
        int k = kt * 32 + ty + r * 8;
        tile[ty + r * 8][tx] = src[k * 256 + ct * 32 + tx];   // coalesced read
    }
    __syncthreads();
#pragma unroll
    for (int r = 0; r < 4; r++) {
        int c = ct * 32 + ty + r * 8;
        dst[c * 256 + kt * 32 + tx] = (f16)tile[tx][ty + r * 8];  // coalesced write
    }
}

// ---------------- fused SIREN ----------------
__device__ inline f16x8 lds_ld8(const f16* p) {
    // two 8B LDS loads (rows are 8B- but not 16B-aligned with LDST=260)
    f16x4 lo = *(const f16x4*)p;
    f16x4 hi = *(const f16x4*)(p + 4);
    return __builtin_shufflevector(lo, hi, 0, 1, 2, 3, 4, 5, 6, 7);
}

__global__ __launch_bounds__(512, 2)
void siren_fused(const float* __restrict__ coords,
                 const float* __restrict__ ow1, const float* __restrict__ ob1,
                 const float* __restrict__ ow2, const float* __restrict__ ob2,
                 const float* __restrict__ w0, const float* __restrict__ b0,
                 const f16* __restrict__ wt,    // [4][256][256] f16, transposed (c-major)
                 const float* __restrict__ bh,  // [4][256]
                 const float* __restrict__ wf,  // [256]
                 const float* __restrict__ bf,  // [1]
                 float* __restrict__ out) {
    __shared__ __align__(16) f16 Xs[MT * LDST];   // 133120 B activations
    __shared__ float om_rev[MT];                  // omega / (2*pi)
    __shared__ __align__(16) float crd[MT * 4];
    __shared__ __align__(16) float bh_s[256];
    __shared__ __align__(16) float wf_s[256];

    const int t = threadIdx.x;
    const long base_pt = (long)blockIdx.x * MT;

    // ---- stage coords + wf ----
    if (t < 256) {
        ((f32x4*)crd)[t] = ((const f32x4*)(coords + base_pt * 4))[t];
        wf_s[t] = wf[t];
    }
    __syncthreads();

    // ---- omega predictor (fp32 vector; threads 0..255, one point each) ----
    if (t < 256) {
        const float c0 = crd[t * 4], c1 = crd[t * 4 + 1], c2 = crd[t * 4 + 2], c3 = crd[t * 4 + 3];
        float h[64];
#pragma unroll
        for (int j = 0; j < 64; j++) {
            float z = ob1[j] + c0 * ow1[j] + c1 * ow1[64 + j] + c2 * ow1[128 + j] + c3 * ow1[192 + j];
            h[j] = fmaxf(z, 0.f);
        }
        float z2 = ob2[0];
#pragma unroll
        for (int j = 0; j < 64; j++) z2 += h[j] * ow2[j];
        const float sig = 1.f / (1.f + __expf(-z2));
        om_rev[t] = (10.f + 90.f * sig) * INV2PI;
    }
    __syncthreads();

    // ---- layer 0 (K=4, fp32 vector): X = sin(omega*(coords@w0+b0)) ----
    {
        const int pt = t >> 1;
        const int ch = (t & 1) * 128;
        const float c0 = crd[pt * 4], c1 = crd[pt * 4 + 1], c2 = crd[pt * 4 + 2], c3 = crd[pt * 4 + 3];
        const float orv = om_rev[pt];
#pragma unroll 4
        for (int c = 0; c < 128; c += 4) {
            f32x4 wv0 = *(const f32x4*)(w0 + 0 * 256 + ch + c);
            f32x4 wv1 = *(const f32x4*)(w0 + 1 * 256 + ch + c);
            f32x4 wv2 = *(const f32x4*)(w0 + 2 * 256 + ch + c);
            f32x4 wv3 = *(const f32x4*)(w0 + 3 * 256 + ch + c);
            f32x4 bv  = *(const f32x4*)(b0 + ch + c);
            f16x4 r;
#pragma unroll
            for (int j = 0; j < 4; j++) {
                float z = bv[j] + c0 * wv0[j] + c1 * wv1[j] + c2 * wv2[j] + c3 * wv3[j];
                r[j] = (f16)__builtin_amdgcn_sinf(orv * z);
            }
            *(f16x4*)&Xs[pt * LDST + ch + c] = r;
        }
    }
    __syncthreads();

    // ---- hidden layers: Z^T = Wt (A) x X (B), 32x32x16 f16 MFMA ----
    // wave tile: 128 wcols (ct=4) x 64 prows (rt=2); 2 wcol-groups x 4 prow-groups
    // B-LDS bytes/MFMA = 1024/4 = 256 -> LDS ceiling ~67% of MFMA peak.
    const int lane = t & 63;
    const int wave = t >> 6;          // 8 waves
    const int l31 = lane & 31;
    const int lh = lane >> 5;         // half-wave: k-offset 8
    const int wc0 = (wave & 1) * 128; // 128 output cols per wave
    const int pr0 = (wave >> 1) * 64; // 64 point-rows per wave

    for (int layer = 0; layer < 4; layer++) {
        if (t < 256) bh_s[t] = bh[layer * 256 + t];   // consumed after mid-barrier

        const f16* wtl = wt + layer * 65536;
        const f16* aptr = wtl + (wc0 + l31) * 256 + lh * 8;   // A: lane row = wcol
        const f16* bptr = &Xs[(pr0 + l31) * LDST + lh * 8];   // B: lane row = prow

        f32x16 acc[4][2];
#pragma unroll
        for (int ct = 0; ct < 4; ct++)
#pragma unroll
            for (int rt = 0; rt < 2; rt++)
#pragma unroll
                for (int j = 0; j < 16; j++) acc[ct][rt][j] = 0.f;

        // software-pipelined K-loop: prefetch k+16 while MFMAs consume k
        f16x8 av[4], bv[2];
#pragma unroll
        for (int ct = 0; ct < 4; ct++) av[ct] = *(const f16x8*)(aptr + ct * 32 * 256);
#pragma unroll
        for (int rt = 0; rt < 2; rt++) bv[rt] = lds_ld8(bptr + rt * 32 * LDST);

#pragma unroll
        for (int k0 = 0; k0 < 256; k0 += 16) {
            f16x8 av_n[4], bv_n[2];
            if (k0 + 16 < 256) {
#pragma unroll
                for (int ct = 0; ct < 4; ct++) av_n[ct] = *(const f16x8*)(aptr + ct * 32 * 256 + k0 + 16);
#pragma unroll
                for (int rt = 0; rt < 2; rt++) bv_n[rt] = lds_ld8(bptr + rt * 32 * LDST + k0 + 16);
            }
#pragma unroll
            for (int ct = 0; ct < 4; ct++) {
                acc[ct][0] = __builtin_amdgcn_mfma_f32_32x32x16_f16(av[ct], bv[0], acc[ct][0], 0, 0, 0);
                acc[ct][1] = __builtin_amdgcn_mfma_f32_32x32x16_f16(av[ct], bv[1], acc[ct][1], 0, 0, 0);
            }
#pragma unroll
            for (int ct = 0; ct < 4; ct++) av[ct] = av_n[ct];
#pragma unroll
            for (int rt = 0; rt < 2; rt++) bv[rt] = bv_n[rt];
        }
        __syncthreads();   // all Xs reads done; bh_s staged

        // epilogue: x = sin(om*(z+b)), write f16 back to Xs
        float orv[2];
#pragma unroll
        for (int rt = 0; rt < 2; rt++) orv[rt] = om_rev[pr0 + rt * 32 + l31];
#pragma unroll
        for (int ct = 0; ct < 4; ct++) {
#pragma unroll
            for (int g = 0; g < 4; g++) {
                const int wc = wc0 + ct * 32 + g * 8 + lh * 4;  // D row = (reg&3)+8*(reg>>2)+4*lh
                f32x4 bb = *(const f32x4*)&bh_s[wc];
#pragma unroll
                for (int rt = 0; rt < 2; rt++) {
                    const int prow = pr0 + rt * 32 + l31;       // D col = lane&31
                    f16x4 r;
#pragma unroll
                    for (int j = 0; j < 4; j++) {
                        float z = acc[ct][rt][g * 4 + j] + bb[j];
                        r[j] = (f16)__builtin_amdgcn_sinf(orv[rt] * z);
                    }
                    *(f16x4*)&Xs[prow * LDST + wc] = r;         // packed 8B write
                }
            }
        }
        __syncthreads();
    }

    // ---- final layer: out = X @ wf + bf (fp32 vector) ----
    {
        const int pt = t >> 1;
        const int ch = (t & 1) * 128;
        const f16* xrow = &Xs[pt * LDST + ch];
        float s = 0.f;
#pragma unroll 8
        for (int c = 0; c < 128; c += 4) {
            f16x4 xv = *(const f16x4*)(xrow + c);
            f32x4 wv = *(const f32x4*)&wf_s[ch + c];
            s += (float)xv[0] * wv[0] + (float)xv[1] * wv[1]
               + (float)xv[2] * wv[2] + (float)xv[3] * wv[3];
        }
        s += __shfl_xor(s, 1, 64);
        if ((t & 1) == 0) out[base_pt + pt] = s + bf[0];
    }
}

extern "C" void kernel_launch(void* const* d_in, const int* in_sizes, int n_in,
                              void* d_out, int out_size, void* d_ws, size_t ws_size,
                              hipStream_t stream) {
    (void)in_sizes; (void)n_in; (void)out_size; (void)ws_size;
    const float* coords = (const float*)d_in[0];
    const float* ow1 = (const float*)d_in[1];
    const float* ob1 = (const float*)d_in[2];
    const float* ow2 = (const float*)d_in[3];
    const float* ob2 = (const float*)d_in[4];
    const float* w0  = (const float*)d_in[5];
    const float* b0  = (const float*)d_in[6];
    const float* wh  = (const float*)d_in[7];
    const float* bh  = (const float*)d_in[8];
    const float* wf  = (const float*)d_in[9];
    const float* bf  = (const float*)d_in[10];
    float* out = (float*)d_out;
    f16* wt = (f16*)d_ws;   // 4*256*256 f16 = 512 KB

    prep_wt<<<256, 256, 0, stream>>>(wh, wt);
    siren_fused<<<524288 / MT, 512, 0, stream>>>(coords, ow1, ob1, ow2, ob2,
                                                 w0, b0, wt, bh, wf, bf, out);
}

// Round 3
// 520.396 us; speedup vs baseline: 1.4914x; 1.4914x over previous
//
#include <hip/hip_runtime.h>
#include <hip/hip_bf16.h>

typedef _Float16 f16;
typedef f16 f16x4 __attribute__((ext_vector_type(4)));
typedef f16 f16x8 __attribute__((ext_vector_type(8)));
typedef float f32x4 __attribute__((ext_vector_type(4)));
typedef float f32x16 __attribute__((ext_vector_type(16)));

#define MT 256          // points per block
#define LDST 260        // f16 LDS row stride: 520 B -> 2-way (free) bank pattern, 8B aligned
#define INV2PI 0.15915494309189535f

// ---------------- prep: fragment-major Wt ----------------
// wt layout: frag[(layer*8 + wcblk)*16 + kblk][lane][8]  (1 KB per frag, lane-major)
// A[i=lane&31][k = kblk*16 + (lane>>5)*8 + j] = wh[layer][k][wcblk*32 + (lane&31)]
__global__ __launch_bounds__(64)
void prep_wt(const float* __restrict__ wh, f16* __restrict__ wt) {
    const int b = blockIdx.x;                 // 512 = layer(4) x wcblk(8) x kblk(16)
    const int layer = b >> 7, wcblk = (b >> 4) & 7, kblk = b & 15;
    const int lane = threadIdx.x;
    const int l31 = lane & 31, lh = lane >> 5;
    const float* src = wh + layer * 65536 + (kblk * 16 + lh * 8) * 256 + wcblk * 32 + l31;
    f16x8 v;
#pragma unroll
    for (int j = 0; j < 8; j++) v[j] = (f16)src[j * 256];   // 128B-coalesced per half-wave
    *(f16x8*)(wt + b * 512 + lane * 8) = v;                  // 1KB coalesced store
}

// ---------------- fused SIREN ----------------
__device__ inline f16x8 lds_ld8(const f16* p) {
    // two 8B LDS loads (rows are 8B- but not 16B-aligned with LDST=260)
    f16x4 lo = *(const f16x4*)p;
    f16x4 hi = *(const f16x4*)(p + 4);
    return __builtin_shufflevector(lo, hi, 0, 1, 2, 3, 4, 5, 6, 7);
}

__global__ __launch_bounds__(512, 2)
void siren_fused(const float* __restrict__ coords,
                 const float* __restrict__ ow1, const float* __restrict__ ob1,
                 const float* __restrict__ ow2, const float* __restrict__ ob2,
                 const float* __restrict__ w0, const float* __restrict__ b0,
                 const f16* __restrict__ wt,    // fragment-major, see prep_wt
                 const float* __restrict__ bh,  // [4][256]
                 const float* __restrict__ wf,  // [256]
                 const float* __restrict__ bf,  // [1]
                 float* __restrict__ out) {
    __shared__ __align__(16) f16 Xs[MT * LDST];   // 133120 B activations
    __shared__ float om_rev[MT];                  // omega / (2*pi)
    __shared__ __align__(16) float crd[MT * 4];
    __shared__ __align__(16) float bh_s[256];
    __shared__ __align__(16) float wf_s[256];

    const int t = threadIdx.x;
    const long base_pt = (long)blockIdx.x * MT;

    // ---- stage coords + wf ----
    if (t < 256) {
        ((f32x4*)crd)[t] = ((const f32x4*)(coords + base_pt * 4))[t];
        wf_s[t] = wf[t];
    }
    __syncthreads();

    // ---- omega predictor (fp32 vector; threads 0..255, one point each) ----
    if (t < 256) {
        const float c0 = crd[t * 4], c1 = crd[t * 4 + 1], c2 = crd[t * 4 + 2], c3 = crd[t * 4 + 3];
        float h[64];
#pragma unroll
        for (int j = 0; j < 64; j++) {
            float z = ob1[j] + c0 * ow1[j] + c1 * ow1[64 + j] + c2 * ow1[128 + j] + c3 * ow1[192 + j];
            h[j] = fmaxf(z, 0.f);
        }
        float z2 = ob2[0];
#pragma unroll
        for (int j = 0; j < 64; j++) z2 += h[j] * ow2[j];
        const float sig = 1.f / (1.f + __expf(-z2));
        om_rev[t] = (10.f + 90.f * sig) * INV2PI;
    }
    __syncthreads();

    // ---- layer 0 (K=4, fp32 vector): X = sin(omega*(coords@w0+b0)) ----
    {
        const int pt = t >> 1;
        const int ch = (t & 1) * 128;
        const float c0 = crd[pt * 4], c1 = crd[pt * 4 + 1], c2 = crd[pt * 4 + 2], c3 = crd[pt * 4 + 3];
        const float orv = om_rev[pt];
#pragma unroll 4
        for (int c = 0; c < 128; c += 4) {
            f32x4 wv0 = *(const f32x4*)(w0 + 0 * 256 + ch + c);
            f32x4 wv1 = *(const f32x4*)(w0 + 1 * 256 + ch + c);
            f32x4 wv2 = *(const f32x4*)(w0 + 2 * 256 + ch + c);
            f32x4 wv3 = *(const f32x4*)(w0 + 3 * 256 + ch + c);
            f32x4 bv  = *(const f32x4*)(b0 + ch + c);
            f16x4 r;
#pragma unroll
            for (int j = 0; j < 4; j++) {
                float z = bv[j] + c0 * wv0[j] + c1 * wv1[j] + c2 * wv2[j] + c3 * wv3[j];
                r[j] = (f16)__builtin_amdgcn_sinf(orv * z);
            }
            *(f16x4*)&Xs[pt * LDST + ch + c] = r;
        }
    }
    __syncthreads();

    // ---- hidden layers: Z^T = Wt (A) x X (B), 32x32x16 f16 MFMA ----
    // wave tile: 64 wcols (ct=2) x 128 prows (rt=4); A coalesced 1KB frag loads,
    // B from LDS. Per CU-layer: A ~4096 cyc (L1), B ~4096 cyc (LDS), MFMA 2048.
    const int lane = t & 63;
    const int wave = t >> 6;          // 8 waves
    const int l31 = lane & 31;
    const int lh = lane >> 5;         // half-wave: k-offset 8
    const int wc0 = (wave & 3) * 64;  // 64 output cols per wave
    const int pr0 = (wave >> 2) * 128;// 128 point-rows per wave

    for (int layer = 0; layer < 4; layer++) {
        if (t < 256) bh_s[t] = bh[layer * 256 + t];   // consumed after mid-barrier

        // A frags for this wave: wcblk0 = (wave&3)*2, frags are 512-f16 apart
        const f16* afrag = wt + ((layer * 8 + (wave & 3) * 2) * 16) * 512 + lane * 8;
        const f16* bptr = &Xs[(pr0 + l31) * LDST + lh * 8];   // B: lane row = prow

        f32x16 acc[2][4];
#pragma unroll
        for (int ct = 0; ct < 2; ct++)
#pragma unroll
            for (int rt = 0; rt < 4; rt++)
#pragma unroll
                for (int j = 0; j < 16; j++) acc[ct][rt][j] = 0.f;

#pragma unroll
        for (int kb = 0; kb < 16; kb++) {
            f16x8 av0 = *(const f16x8*)(afrag + kb * 512);          // coalesced 1KB
            f16x8 av1 = *(const f16x8*)(afrag + 8192 + kb * 512);   // next wcblk
            f16x8 bv[4];
#pragma unroll
            for (int rt = 0; rt < 4; rt++) bv[rt] = lds_ld8(bptr + rt * 32 * LDST + kb * 16);
#pragma unroll
            for (int rt = 0; rt < 4; rt++) {
                acc[0][rt] = __builtin_amdgcn_mfma_f32_32x32x16_f16(av0, bv[rt], acc[0][rt], 0, 0, 0);
                acc[1][rt] = __builtin_amdgcn_mfma_f32_32x32x16_f16(av1, bv[rt], acc[1][rt], 0, 0, 0);
            }
        }
        __syncthreads();   // all Xs reads done; bh_s staged

        // epilogue: x = sin(om*(z+b)), write f16 back to Xs
        float orv[4];
#pragma unroll
        for (int rt = 0; rt < 4; rt++) orv[rt] = om_rev[pr0 + rt * 32 + l31];
#pragma unroll
        for (int ct = 0; ct < 2; ct++) {
#pragma unroll
            for (int g = 0; g < 4; g++) {
                const int wc = wc0 + ct * 32 + g * 8 + lh * 4;  // D row = (reg&3)+8*(reg>>2)+4*lh
                f32x4 bb = *(const f32x4*)&bh_s[wc];
#pragma unroll
                for (int rt = 0; rt < 4; rt++) {
                    const int prow = pr0 + rt * 32 + l31;       // D col = lane&31
                    f16x4 r;
#pragma unroll
                    for (int j = 0; j < 4; j++) {
                        float z = acc[ct][rt][g * 4 + j] + bb[j];
                        r[j] = (f16)__builtin_amdgcn_sinf(orv[rt] * z);
                    }
                    *(f16x4*)&Xs[prow * LDST + wc] = r;         // packed 8B write
                }
            }
        }
        __syncthreads();
    }

    // ---- final layer: out = X @ wf + bf (fp32 vector) ----
    {
        const int pt = t >> 1;
        const int ch = (t & 1) * 128;
        const f16* xrow = &Xs[pt * LDST + ch];
        float s = 0.f;
#pragma unroll 8
        for (int c = 0; c < 128; c += 4) {
            f16x4 xv = *(const f16x4*)(xrow + c);
            f32x4 wv = *(const f32x4*)&wf_s[ch + c];
            s += (float)xv[0] * wv[0] + (float)xv[1] * wv[1]
               + (float)xv[2] * wv[2] + (float)xv[3] * wv[3];
        }
        s += __shfl_xor(s, 1, 64);
        if ((t & 1) == 0) out[base_pt + pt] = s + bf[0];
    }
}

extern "C" void kernel_launch(void* const* d_in, const int* in_sizes, int n_in,
                              void* d_out, int out_size, void* d_ws, size_t ws_size,
                              hipStream_t stream) {
    (void)in_sizes; (void)n_in; (void)out_size; (void)ws_size;
    const float* coords = (const float*)d_in[0];
    const float* ow1 = (const float*)d_in[1];
    const float* ob1 = (const float*)d_in[2];
    const float* ow2 = (const float*)d_in[3];
    const float* ob2 = (const float*)d_in[4];
    const float* w0  = (const float*)d_in[5];
    const float* b0  = (const float*)d_in[6];
    const float* wh  = (const float*)d_in[7];
    const float* bh  = (const float*)d_in[8];
    const float* wf  = (const float*)d_in[9];
    const float* bf  = (const float*)d_in[10];
    float* out = (float*)d_out;
    f16* wt = (f16*)d_ws;   // 512 frags * 1KB = 512 KB

    prep_wt<<<512, 64, 0, stream>>>(wh, wt);
    siren_fused<<<524288 / MT, 512, 0, stream>>>(coords, ow1, ob1, ow2, ob2,
                                                 w0, b0, wt, bh, wf, bf, out);
}